// Round 9
// baseline (6573.903 us; speedup 1.0000x reference)
//
#include <hip/hip_runtime.h>
#include <hip/hip_fp16.h>
#include <cstddef>
#include <cstdint>

#define B_  256
#define T_  512
#define D_  128
#define H_  256
#define G3_ 768
#define C_  10

typedef _Float16 f16x8 __attribute__((ext_vector_type(8)));
typedef float    f32x4 __attribute__((ext_vector_type(4)));

__device__ __forceinline__ float sigmoid_f(float x) {
    return 1.0f / (1.0f + __expf(-x));
}
__device__ __forceinline__ float tanh_f(float x) {
    return 1.0f - 2.0f / (__expf(2.0f * x) + 1.0f);
}

__device__ __forceinline__ unsigned int packh2(float a, float b) {
    unsigned short lo = __half_as_ushort(__float2half(a));   // k even -> lo16
    unsigned short hi = __half_as_ushort(__float2half(b));   // k odd  -> hi16
    return (unsigned int)lo | ((unsigned int)hi << 16);
}

// ---------------------------------------------------------------------------
// Pack Whh[3H][H] fp32 -> f16 MFMA B-fragment stream for the scan.
// Fragment (w8, nt, kt): column-set w8 (0..7) owns gate-cols
// c0 = g*256 + w8*32 + (nt&1)*16 (g = nt>>1), K-tile kt. Lane l supplies
// B[k][n]: n = c0 + (l&15), k = kt*32 + (l>>4)*8 + i.
// (unchanged, harness-verified layout)
// ---------------------------------------------------------------------------
__global__ void k_pack_whh(const float* __restrict__ Whh, uint4* __restrict__ Wl) {
    const int wnt = blockIdx.x;          // w8*6 + nt
    const int w  = wnt / 6;
    const int nt = wnt % 6;
    const int t  = threadIdx.x;
    const int kt = t >> 6;
    const int l  = t & 63;
    const int g  = nt >> 1;
    const int n  = g * 256 + w * 32 + (nt & 1) * 16 + (l & 15);
    const int k0 = kt * 32 + (l >> 4) * 8;
    const float* row = Whh + (size_t)n * H_ + k0;
    uint4 u;
    u.x = packh2(row[0], row[1]);
    u.y = packh2(row[2], row[3]);
    u.z = packh2(row[4], row[5]);
    u.w = packh2(row[6], row[7]);
    Wl[(size_t)wnt * 512 + t] = u;
}

// ---------------------------------------------------------------------------
// Pack Wih[768][K] fp32 -> f16 B-fragments for the gi GEMM. (unchanged)
// ---------------------------------------------------------------------------
__global__ void k_pack_wih(const float* __restrict__ W, uint4* __restrict__ Wp,
                           int K) {
    const int KT = K >> 5;
    const int f  = blockIdx.x * 4 + (threadIdx.x >> 6);
    const int l  = threadIdx.x & 63;
    const int ntile = f / KT;
    const int kt    = f - ntile * KT;
    const int n  = ntile * 16 + (l & 15);
    const int k0 = kt * 32 + (l >> 4) * 8;
    const float* row = W + (size_t)n * K + k0;
    uint4 u;
    u.x = packh2(row[0], row[1]);
    u.y = packh2(row[2], row[3]);
    u.z = packh2(row[4], row[5]);
    u.w = packh2(row[6], row[7]);
    Wp[(size_t)f * 64 + l] = u;
}

// ---------------------------------------------------------------------------
// gi GEMM on the matrix pipe. C written in SCAN-NATIVE order: gate column n
// (g = n>>8, j = n&255, jw = j>>5, cc = j&15, half = (j>>4)&1) lands at
// row-offset ((jw*16+cc)*3 + g)*2 + half. (unchanged from R7)
// ---------------------------------------------------------------------------
__global__ __launch_bounds__(256) void k_gemm_f16(
    const float* __restrict__ A, long Abstride, int tcShift,
    const uint4* __restrict__ Wp,
    const float* __restrict__ bias, float* __restrict__ C,
    int K)
{
    const int tid = threadIdx.x;
    const int w  = tid >> 6;
    const int l  = tid & 63;
    const int c  = l & 15;
    const int g4 = l >> 4;
    const int m0 = blockIdx.y * 128;
    const int n0 = blockIdx.x * 64;
    const int KT = K >> 5;
    const int mask = (1 << tcShift) - 1;

    const float* Arow0;
    const float* Arow1;
    {
        int mg0 = m0 + w * 32 + c;
        int mg1 = mg0 + 16;
        Arow0 = A + (size_t)(mg0 >> tcShift) * Abstride + (size_t)(mg0 & mask) * K + g4 * 8;
        Arow1 = A + (size_t)(mg1 >> tcShift) * Abstride + (size_t)(mg1 & mask) * K + g4 * 8;
    }
    const uint4* Wb = Wp + (size_t)((n0 >> 4) * KT) * 64 + l;

    f32x4 acc[2][4] = {};

    for (int kt = 0; kt < KT; kt++) {
        f16x8 a0, a1;
        {
            float4 lo = *(const float4*)(Arow0 + kt * 32);
            float4 hi = *(const float4*)(Arow0 + kt * 32 + 4);
            a0[0] = (_Float16)lo.x; a0[1] = (_Float16)lo.y;
            a0[2] = (_Float16)lo.z; a0[3] = (_Float16)lo.w;
            a0[4] = (_Float16)hi.x; a0[5] = (_Float16)hi.y;
            a0[6] = (_Float16)hi.z; a0[7] = (_Float16)hi.w;
        }
        {
            float4 lo = *(const float4*)(Arow1 + kt * 32);
            float4 hi = *(const float4*)(Arow1 + kt * 32 + 4);
            a1[0] = (_Float16)lo.x; a1[1] = (_Float16)lo.y;
            a1[2] = (_Float16)lo.z; a1[3] = (_Float16)lo.w;
            a1[4] = (_Float16)hi.x; a1[5] = (_Float16)hi.y;
            a1[6] = (_Float16)hi.z; a1[7] = (_Float16)hi.w;
        }
#pragma unroll
        for (int ct = 0; ct < 4; ct++) {
            uint4 wf = Wb[(size_t)(ct * KT + kt) * 64];
            acc[0][ct] = __builtin_amdgcn_mfma_f32_16x16x32_f16(
                a0, __builtin_bit_cast(f16x8, wf), acc[0][ct], 0, 0, 0);
            acc[1][ct] = __builtin_amdgcn_mfma_f32_16x16x32_f16(
                a1, __builtin_bit_cast(f16x8, wf), acc[1][ct], 0, 0, 0);
        }
    }

#pragma unroll
    for (int ct = 0; ct < 4; ct++) {
        const int n = n0 + ct * 16 + c;
        const float bv = bias[n];
        const int g = n >> 8;
        const int j = n & 255;
        const int sidx = (((j >> 5) * 16 + (j & 15)) * 3 + g) * 2 + ((j >> 4) & 1);
#pragma unroll
        for (int rt = 0; rt < 2; rt++) {
#pragma unroll
            for (int rg = 0; rg < 4; rg++) {
                const int m = m0 + w * 32 + rt * 16 + g4 * 4 + rg;
                C[(size_t)m * G3_ + sidx] = acc[rt][ct][rg] + bv;
            }
        }
    }
}

// ---------------------------------------------------------------------------
// ALL-RESIDENT MFMA scan. 32 blocks x 256 thr (4 waves), 1 wave/SIMD,
// __launch_bounds__(256,1) -> VGPR cap 512. Each wave owns 192 gate-cols =
// 12 nt-planes (col-sets w8a=2w, w8b=2w+1, nt 0..5 each):
//   - 8 planes REGISTER-resident: 64 f16x8 frags = 256 VGPRs, per-step
//     value-laundered (R6-proven: sticks at cap 512; R2/R7 proved it fails
//     at cap 256 -- that's why 8-wave blocks could never hold weights).
//   - 4 planes (w8b nt2..5) in 128 KB LDS.
// ZERO weight bytes streamed per step (R1-R7's ~256KB/step L2 wall deleted).
// 1 wave/SIMD serializes VALU/MFMA/LDS, est ~0.8 us/step vs 2.85 measured
// on the 8-wave streaming structure.
// R6 note stands: cross-CU per-step sync is dead (8.4 us/step) -- this
// design needs none.
// (R8 bench: "container failed twice" = infra flake, no kernel signal;
//  resubmitted unchanged.)
// ---------------------------------------------------------------------------
__device__ __forceinline__ void gru_scan_core(
    const float* __restrict__ gi,      // + b0*Tc*G3   [16 rows][Tc][3H native]
    const uint4* __restrict__ Wpk,     // [48][512] packed B-fragments
    const float* __restrict__ bhh,
    float* __restrict__ h_state,       // + b0*H
    float* __restrict__ out_seq,       // + b0*Tc*H or nullptr
    int Tc, int initZero,
    uint4 (&lds_w)[8192], _Float16 (&lds_h)[2][16][264])
{
    const int tid = threadIdx.x;
    const int w  = tid >> 6;       // wave 0..3
    const int l  = tid & 63;
    const int c  = l & 15;
    const int g4 = l >> 4;         // 0..3
    const int w8a = 2 * w;
    const int w8b = 2 * w + 1;

    // ---- stage LDS planes: (w8b, nt 2..5) for each wave -------------------
    // dest: lds_w[(wv*4 + q)*512 + kt*64 + ln]
#pragma unroll
    for (int i = 0; i < 32; i++) {
        int idx  = i * 256 + tid;
        int pq   = idx >> 9;               // wv*4 + q
        int wv   = pq >> 2;
        int q    = pq & 3;
        int rest = idx & 511;              // kt*64 + ln
        lds_w[idx] = Wpk[(size_t)((2 * wv + 1) * 6 + 2 + q) * 512 + rest];
    }

    // ---- register-resident frags: 8 planes x 8 kt = 64 f16x8 (256 VGPR) --
    f16x8 wreg[64];
#pragma unroll
    for (int p = 0; p < 8; p++) {
        const int plane = (p < 6) ? (w8a * 6 + p) : (w8b * 6 + (p - 6));
#pragma unroll
        for (int kt = 0; kt < 8; kt++)
            wreg[p * 8 + kt] = *reinterpret_cast<const f16x8*>(
                Wpk + (size_t)(plane * 8 + kt) * 64 + l);
    }

    // ---- lane ownership: rows m = g4*4+r; h-cols j0 + {0,16,32,48} --------
    const int j0 = w * 64 + c;
    float br[4], bz[4], bn[4];
#pragma unroll
    for (int cb = 0; cb < 4; cb++) {
        br[cb] = bhh[j0 + cb * 16];
        bz[cb] = bhh[256 + j0 + cb * 16];
        bn[cb] = bhh[512 + j0 + cb * 16];
    }

    int voff_gi[4], voff_os[4];
#pragma unroll
    for (int r = 0; r < 4; r++) {
        const int m = g4 * 4 + r;
        voff_gi[r] = m * Tc * G3_ + (2 * w * 16 + c) * 6;  // jw=2w base; +384B imm for jw+1
        voff_os[r] = m * Tc * H_ + j0;
    }

    float hreg[4][4];
#pragma unroll
    for (int r = 0; r < 4; r++) {
        const int m = g4 * 4 + r;
#pragma unroll
        for (int cb = 0; cb < 4; cb++)
            hreg[r][cb] = initZero ? 0.0f
                                   : h_state[(size_t)m * H_ + j0 + cb * 16];
    }
    // full-width h_{-1} init into lds_h[0] (256 thr cover 16 rows x 256 cols)
    {
        const int row = tid >> 4;
        const int cc  = (tid & 15) * 16;
        _Float16 tmp[16];
        if (initZero) {
#pragma unroll
            for (int i = 0; i < 16; i++) tmp[i] = (_Float16)0.0f;
        } else {
            const float* hp = h_state + (size_t)row * H_ + cc;
#pragma unroll
            for (int i = 0; i < 16; i++) tmp[i] = (_Float16)hp[i];
        }
        *(uint4*)&lds_h[0][row][cc]     = *(const uint4*)&tmp[0];
        *(uint4*)&lds_h[0][row][cc + 8] = *(const uint4*)&tmp[8];
    }
    __syncthreads();

    int cur = 0;
    for (int tt = 0; tt < Tc; ++tt) {
        // ---- anti-remat launder: weights opaque each step (no codegen) ----
#pragma unroll
        for (int i = 0; i < 64; i++)
            asm volatile("" : "+v"(wreg[i]));
        unsigned wb = (unsigned)(w * 2048 + l);
        asm volatile("" : "+v"(wb));

        // gi loads: SGPR step base + invariant voffs + imm offsets
        const float* gstep = gi + (size_t)tt * G3_;
        float2 vg[4][6];
#pragma unroll
        for (int r = 0; r < 4; r++) {
            const float* gp = gstep + voff_gi[r];
            vg[r][0] = *(const float2*)(gp);
            vg[r][1] = *(const float2*)(gp + 2);
            vg[r][2] = *(const float2*)(gp + 4);
            vg[r][3] = *(const float2*)(gp + 96);
            vg[r][4] = *(const float2*)(gp + 98);
            vg[r][5] = *(const float2*)(gp + 100);
        }

        // ---- 96 MFMA: 64 from regs + 32 from LDS --------------------------
        f32x4 acc[12] = {};
#pragma unroll
        for (int kt = 0; kt < 8; kt++) {
            f16x8 a = *(const f16x8*)&lds_h[cur][c][kt * 32 + g4 * 8];
#pragma unroll
            for (int p = 0; p < 8; p++)
                acc[p] = __builtin_amdgcn_mfma_f32_16x16x32_f16(
                    a, wreg[p * 8 + kt], acc[p], 0, 0, 0);
#pragma unroll
            for (int q = 0; q < 4; q++) {
                uint4 u = lds_w[wb + q * 512 + kt * 64];
                acc[8 + q] = __builtin_amdgcn_mfma_f32_16x16x32_f16(
                    a, __builtin_bit_cast(f16x8, u), acc[8 + q], 0, 0, 0);
            }
        }

        // ---- gates + h update ---------------------------------------------
        // acc: [0..5]=w8a nt0..5, [6..7]=w8b nt0..1, [8..11]=w8b nt2..5.
        // cb<2 (w8a): r=acc[hb], z=acc[2+hb], n=acc[4+hb];
        // cb>=2 (w8b): r=acc[6+hb], z=acc[8+hb], n=acc[10+hb].
        float* osb = out_seq ? out_seq + (size_t)tt * H_ : nullptr;
#pragma unroll
        for (int r = 0; r < 4; r++) {
            const int m = g4 * 4 + r;
#pragma unroll
            for (int cb = 0; cb < 4; cb++) {
                const int hb = cb & 1;
                const int vb = (cb >> 1) * 3;
                const float gr = hb ? vg[r][vb + 0].y : vg[r][vb + 0].x;
                const float gz = hb ? vg[r][vb + 1].y : vg[r][vb + 1].x;
                const float gn = hb ? vg[r][vb + 2].y : vg[r][vb + 2].x;
                float ar, az, an;
                if (cb < 2) { ar = acc[hb][r];     az = acc[2 + hb][r]; an = acc[4 + hb][r]; }
                else        { ar = acc[6 + hb][r]; az = acc[8 + hb][r]; an = acc[10 + hb][r]; }
                float rg = sigmoid_f(gr + ar + br[cb]);
                float zg = sigmoid_f(gz + az + bz[cb]);
                float ng = tanh_f(gn + rg * (an + bn[cb]));
                float hn = (1.0f - zg) * ng + zg * hreg[r][cb];
                hreg[r][cb] = hn;
                lds_h[cur ^ 1][m][j0 + cb * 16] = (_Float16)hn;
                if (osb)
                    osb[voff_os[r] + cb * 16] = hn;
            }
        }
        if (tt == Tc - 1) {
#pragma unroll
            for (int r = 0; r < 4; r++) {
                const int m = g4 * 4 + r;
#pragma unroll
                for (int cb = 0; cb < 4; cb++)
                    h_state[(size_t)m * H_ + j0 + cb * 16] = hreg[r][cb];
            }
        }
        __syncthreads();
        cur ^= 1;
    }
}

// Fused layer-pipelined scan: blocks 0..15 -> layer0 chunk c (16 rows each),
// blocks 16..31 -> layer1 chunk c-1. 144.5 KB LDS -> 1 block/CU.
__global__ __launch_bounds__(256, 1) void k_gru_scan_fused(
    const float* __restrict__ gi0, const uint4* __restrict__ wl0,
    const float* __restrict__ bhh0, float* __restrict__ hst0,
    float* __restrict__ h1c,
    const float* __restrict__ gi1, const uint4* __restrict__ wl1,
    const float* __restrict__ bhh1, float* __restrict__ hst1,
    int Tc, int do0, int do1, int init0, int init1)
{
    __shared__ __align__(16) uint4    lds_w[8192];        // 128 KB
    __shared__ __align__(16) _Float16 lds_h[2][16][264];  // 16.5 KB

    const int blk = blockIdx.x;
    if (blk < 16) {
        if (!do0) return;
        const int b0 = blk * 16;
        gru_scan_core(gi0 + (size_t)b0 * Tc * G3_, wl0, bhh0,
                      hst0 + (size_t)b0 * H_, h1c + (size_t)b0 * Tc * H_,
                      Tc, init0, lds_w, lds_h);
    } else {
        if (!do1) return;
        const int b0 = (blk - 16) * 16;
        gru_scan_core(gi1 + (size_t)b0 * Tc * G3_, wl1, bhh1,
                      hst1 + (size_t)b0 * H_, nullptr,
                      Tc, init1, lds_w, lds_h);
    }
}

// ---------------------------------------------------------------------------
__global__ void k_fc(const float* __restrict__ h, const float* __restrict__ Wfc,
                     const float* __restrict__ bfc, float* __restrict__ out)
{
    int idx = blockIdx.x * blockDim.x + threadIdx.x;
    if (idx >= B_ * C_) return;
    int b = idx / C_, c = idx % C_;
    const float* hp = h + (size_t)b * H_;
    const float* wp = Wfc + (size_t)c * H_;
    float s = bfc[c];
#pragma unroll 4
    for (int k = 0; k < H_; k++) s = fmaf(hp[k], wp[k], s);
    out[idx] = s;
}

// ---------------------------------------------------------------------------
extern "C" void kernel_launch(void* const* d_in, const int* in_sizes, int n_in,
                              void* d_out, int out_size, void* d_ws, size_t ws_size,
                              hipStream_t stream)
{
    const float* x    = (const float*)d_in[0];
    const float* Wih0 = (const float*)d_in[1];
    const float* Whh0 = (const float*)d_in[2];
    const float* bih0 = (const float*)d_in[3];
    const float* bhh0 = (const float*)d_in[4];
    const float* Wih1 = (const float*)d_in[5];
    const float* Whh1 = (const float*)d_in[6];
    const float* bih1 = (const float*)d_in[7];
    const float* bhh1 = (const float*)d_in[8];
    const float* Wfc  = (const float*)d_in[9];
    const float* bfc  = (const float*)d_in[10];
    float* out = (float*)d_out;

    const size_t wlBytes  = (size_t)48 * 512 * sizeof(uint4);    // 393,216 B
    const size_t wp0Bytes = (size_t)48 * 4 * 64 * sizeof(uint4); // 196,608 B
    const size_t wp1Bytes = (size_t)48 * 8 * 64 * sizeof(uint4); // 393,216 B

    // ---- largest power-of-two T-chunk that fits ws_size -------------------
    const size_t fixedB = 2 * wlBytes + wp0Bytes + wp1Bytes
                        + 2 * (size_t)B_ * H_ * 4 + 16384;
    int Tc = 128, tcShift = 7;
    while (Tc > 1) {
        size_t need = fixedB
                    + 2 * (size_t)B_ * Tc * G3_ * 4    // gi0, gi1 chunks
                    + (size_t)B_ * Tc * H_ * 4;        // h1 chunk
        if (need <= ws_size) break;
        Tc >>= 1; tcShift--;
    }
    const int nChunks = T_ / Tc;

    char* ws = (char*)d_ws;
    size_t off = 0;
    auto alloc = [&](size_t bytes) { char* p = ws + off; off += (bytes + 255) & ~(size_t)255; return p; };
    float* gi0  = (float*)alloc((size_t)B_ * Tc * G3_ * 4);
    float* gi1  = (float*)alloc((size_t)B_ * Tc * G3_ * 4);
    float* h1c  = (float*)alloc((size_t)B_ * Tc * H_ * 4);
    uint4* wl0  = (uint4*)alloc(wlBytes);
    uint4* wl1  = (uint4*)alloc(wlBytes);
    uint4* wp0  = (uint4*)alloc(wp0Bytes);
    uint4* wp1  = (uint4*)alloc(wp1Bytes);
    float* hst0 = (float*)alloc((size_t)B_ * H_ * 4);
    float* hst1 = (float*)alloc((size_t)B_ * H_ * 4);

    k_pack_whh<<<48, 512, 0, stream>>>(Whh0, wl0);
    k_pack_whh<<<48, 512, 0, stream>>>(Whh1, wl1);
    k_pack_wih<<<48, 256, 0, stream>>>(Wih0, wp0, D_);   // KT=4 -> 192 frags
    k_pack_wih<<<96, 256, 0, stream>>>(Wih1, wp1, H_);   // KT=8 -> 384 frags

    const dim3 ggrid(G3_ / 64, (B_ * Tc) / 128);

    // software pipeline: fused launch c runs scan0(c) and scan1(c-1)
    k_gemm_f16<<<ggrid, 256, 0, stream>>>(
        x, (long)T_ * D_, tcShift, wp0, bih0, gi0, D_);
    k_gru_scan_fused<<<32, 256, 0, stream>>>(
        gi0, wl0, bhh0, hst0, h1c, gi1, wl1, bhh1, hst1,
        Tc, 1, 0, 1, 0);

    for (int c = 1; c < nChunks; ++c) {
        k_gemm_f16<<<ggrid, 256, 0, stream>>>(
            h1c, (long)Tc * H_, tcShift, wp1, bih1, gi1, H_);        // chunk c-1
        k_gemm_f16<<<ggrid, 256, 0, stream>>>(
            x + (size_t)c * Tc * D_, (long)T_ * D_, tcShift, wp0, bih0, gi0, D_);
        k_gru_scan_fused<<<32, 256, 0, stream>>>(
            gi0, wl0, bhh0, hst0, h1c, gi1, wl1, bhh1, hst1,
            Tc, 1, 1, 0, c == 1);
    }

    k_gemm_f16<<<ggrid, 256, 0, stream>>>(
        h1c, (long)Tc * H_, tcShift, wp1, bih1, gi1, H_);            // last chunk
    k_gru_scan_fused<<<32, 256, 0, stream>>>(
        gi0, wl0, bhh0, hst0, h1c, gi1, wl1, bhh1, hst1,
        Tc, 0, 1, 0, nChunks == 1);

    k_fc<<<10, 256, 0, stream>>>(hst1, Wfc, bfc, out);
}

// Round 10
// 2254.136 us; speedup vs baseline: 2.9164x; 2.9164x over previous
//
#include <hip/hip_runtime.h>
#include <hip/hip_fp16.h>
#include <cstddef>
#include <cstdint>

#define B_  256
#define T_  512
#define D_  128
#define H_  256
#define G3_ 768
#define C_  10

typedef _Float16 f16x8 __attribute__((ext_vector_type(8)));
typedef float    f32x4 __attribute__((ext_vector_type(4)));

__device__ __forceinline__ float sigmoid_f(float x) {
    return 1.0f / (1.0f + __expf(-x));
}
__device__ __forceinline__ float tanh_f(float x) {
    return 1.0f - 2.0f / (__expf(2.0f * x) + 1.0f);
}

__device__ __forceinline__ unsigned int packh2(float a, float b) {
    unsigned short lo = __half_as_ushort(__float2half(a));   // k even -> lo16
    unsigned short hi = __half_as_ushort(__float2half(b));   // k odd  -> hi16
    return (unsigned int)lo | ((unsigned int)hi << 16);
}

// ---------------------------------------------------------------------------
// Pack Whh[3H][H] fp32 -> f16 MFMA B-fragment stream for the scan.
// Fragment (w, nt, kt): wave w owns gate-cols c0 = g*256 + w*32 + (nt&1)*16
// (g = nt>>1), K-tile kt. Lane l: n = c0 + (l&15), k = kt*32 + (l>>4)*8 + i.
// (unchanged, harness-verified layout)
// ---------------------------------------------------------------------------
__global__ void k_pack_whh(const float* __restrict__ Whh, uint4* __restrict__ Wl) {
    const int wnt = blockIdx.x;          // w*6 + nt
    const int w  = wnt / 6;
    const int nt = wnt % 6;
    const int t  = threadIdx.x;
    const int kt = t >> 6;
    const int l  = t & 63;
    const int g  = nt >> 1;
    const int n  = g * 256 + w * 32 + (nt & 1) * 16 + (l & 15);
    const int k0 = kt * 32 + (l >> 4) * 8;
    const float* row = Whh + (size_t)n * H_ + k0;
    uint4 u;
    u.x = packh2(row[0], row[1]);
    u.y = packh2(row[2], row[3]);
    u.z = packh2(row[4], row[5]);
    u.w = packh2(row[6], row[7]);
    Wl[(size_t)wnt * 512 + t] = u;
}

// ---------------------------------------------------------------------------
// Pack Wih[768][K] fp32 -> f16 B-fragments for the gi GEMM. (unchanged)
// ---------------------------------------------------------------------------
__global__ void k_pack_wih(const float* __restrict__ W, uint4* __restrict__ Wp,
                           int K) {
    const int KT = K >> 5;
    const int f  = blockIdx.x * 4 + (threadIdx.x >> 6);
    const int l  = threadIdx.x & 63;
    const int ntile = f / KT;
    const int kt    = f - ntile * KT;
    const int n  = ntile * 16 + (l & 15);
    const int k0 = kt * 32 + (l >> 4) * 8;
    const float* row = W + (size_t)n * K + k0;
    uint4 u;
    u.x = packh2(row[0], row[1]);
    u.y = packh2(row[2], row[3]);
    u.z = packh2(row[4], row[5]);
    u.w = packh2(row[6], row[7]);
    Wp[(size_t)f * 64 + l] = u;
}

// ---------------------------------------------------------------------------
// gi GEMM on the matrix pipe: C[M,768] = A[M,K](f32->f16) @ W^T(f16) + bias.
// R10 change: n-tile widened 64 -> 128 (ct 0..7, grid.x = 6). Halves the
// number of blocks re-reading each A-tile (12 -> 6) -- the measured ~62 us
// per dispatch vs ~17 us memory floor was dominated by redundant A traffic.
// C layout NORMAL (row m, col n), matching the R4-proven scan reader.
// ---------------------------------------------------------------------------
__global__ __launch_bounds__(256) void k_gemm_f16(
    const float* __restrict__ A, long Abstride, int tcShift,
    const uint4* __restrict__ Wp,
    const float* __restrict__ bias, float* __restrict__ C,
    int K)
{
    const int tid = threadIdx.x;
    const int w  = tid >> 6;
    const int l  = tid & 63;
    const int c  = l & 15;
    const int g4 = l >> 4;
    const int m0 = blockIdx.y * 128;
    const int n0 = blockIdx.x * 128;
    const int KT = K >> 5;
    const int mask = (1 << tcShift) - 1;

    const float* Arow0;
    const float* Arow1;
    {
        int mg0 = m0 + w * 32 + c;
        int mg1 = mg0 + 16;
        Arow0 = A + (size_t)(mg0 >> tcShift) * Abstride + (size_t)(mg0 & mask) * K + g4 * 8;
        Arow1 = A + (size_t)(mg1 >> tcShift) * Abstride + (size_t)(mg1 & mask) * K + g4 * 8;
    }
    const uint4* Wb = Wp + (size_t)((n0 >> 4) * KT) * 64 + l;

    f32x4 acc[2][8] = {};

    for (int kt = 0; kt < KT; kt++) {
        f16x8 a0, a1;
        {
            float4 lo = *(const float4*)(Arow0 + kt * 32);
            float4 hi = *(const float4*)(Arow0 + kt * 32 + 4);
            a0[0] = (_Float16)lo.x; a0[1] = (_Float16)lo.y;
            a0[2] = (_Float16)lo.z; a0[3] = (_Float16)lo.w;
            a0[4] = (_Float16)hi.x; a0[5] = (_Float16)hi.y;
            a0[6] = (_Float16)hi.z; a0[7] = (_Float16)hi.w;
        }
        {
            float4 lo = *(const float4*)(Arow1 + kt * 32);
            float4 hi = *(const float4*)(Arow1 + kt * 32 + 4);
            a1[0] = (_Float16)lo.x; a1[1] = (_Float16)lo.y;
            a1[2] = (_Float16)lo.z; a1[3] = (_Float16)lo.w;
            a1[4] = (_Float16)hi.x; a1[5] = (_Float16)hi.y;
            a1[6] = (_Float16)hi.z; a1[7] = (_Float16)hi.w;
        }
#pragma unroll
        for (int ct = 0; ct < 8; ct++) {
            uint4 wf = Wb[(size_t)(ct * KT + kt) * 64];
            acc[0][ct] = __builtin_amdgcn_mfma_f32_16x16x32_f16(
                a0, __builtin_bit_cast(f16x8, wf), acc[0][ct], 0, 0, 0);
            acc[1][ct] = __builtin_amdgcn_mfma_f32_16x16x32_f16(
                a1, __builtin_bit_cast(f16x8, wf), acc[1][ct], 0, 0, 0);
        }
    }

    // D layout: row = tile_row0 + g4*4 + reg, col = tile_col0 + c (verified).
#pragma unroll
    for (int ct = 0; ct < 8; ct++) {
        const int n = n0 + ct * 16 + c;
        const float bv = bias[n];
#pragma unroll
        for (int rt = 0; rt < 2; rt++) {
#pragma unroll
            for (int rg = 0; rg < 4; rg++) {
                const int m = m0 + w * 32 + rt * 16 + g4 * 4 + rg;
                C[(size_t)m * G3_ + n] = acc[rt][ct][rg] + bv;
            }
        }
    }
}

// ---------------------------------------------------------------------------
// MFMA scan -- EXACT R4 structure (365 us @ Tc=128 measured; VGPR 124).
// The allocator's remat-from-L2 of the 32 weight frags per step is the
// cheapest observed weight path for this structure. Final verdicts:
//   R2 "+v" launder @ cap256: AGPR shuttle, 382 us.
//   R3 "+a" pin: MFMA/accvgpr hazard stalls, 1145 us.
//   R6 partner-split (cross-CU per-step sync): 8.4 us/step -- dead.
//   R7 batched loads + value launder: full-wait, no overlap, 584 us.
//   R9 64-frag residency @ "cap 512": v0-v255 is the HARD addressable cap;
//      VGPR_Count=256 + shuttle at 1 wave/SIMD, 1248 us -- line closed.
// R10: code untouched; Tc shrunk 128->64 at the launch level (total scan
// time = (T + Tc) * 2.85 us -- the layer-pipeline bubble costs one chunk).
// ---------------------------------------------------------------------------
__device__ __forceinline__ void gru_scan_core(
    const float* __restrict__ gi,      // + b0*Tc*G3   [16 rows][Tc][3H]
    const uint4* __restrict__ Wpk,     // [48*8][64] packed B-fragments
    const float* __restrict__ bhh,
    float* __restrict__ h_state,       // + b0*H
    float* __restrict__ out_seq,       // + b0*Tc*H or nullptr
    int Tc, int initZero,
    uint4 (&lds_w)[8192], _Float16 (&lds_h)[2][16][264])
{
    const int tid = threadIdx.x;
    const int w  = tid >> 6;       // wave 0..7
    const int l  = tid & 63;
    const int c  = l & 15;
    const int g4 = l >> 4;         // 0..3

    // ---- stage LDS-resident weight frags (nt 4,5 of every wave) -----------
#pragma unroll
    for (int i = 0; i < 16; i++) {
        int idx = i * 512 + tid;                       // (wv*16 + fl)*64 + ln
        lds_w[idx] = Wpk[(size_t)(idx >> 10) * 3072 + 2048 + (idx & 1023)];
    }

    // ---- register-resident frags: nt 0..3 x kt 0..7 -----------------------
    uint4 wreg[32];
#pragma unroll
    for (int nt = 0; nt < 4; nt++)
#pragma unroll
        for (int kt = 0; kt < 8; kt++)
            wreg[nt * 8 + kt] = Wpk[(size_t)((w * 6 + nt) * 8 + kt) * 64 + l];

    // ---- lane ownership: m = g4*4+r, j = w*32 + jj*16 + c -----------------
    const int jA = w * 32 + c;
    const float br0 = bhh[jA],       br1 = bhh[jA + 16];
    const float bz0 = bhh[256 + jA], bz1 = bhh[256 + jA + 16];
    const float bn0 = bhh[512 + jA], bn1 = bhh[512 + jA + 16];

    float hreg[4][2];
#pragma unroll
    for (int r = 0; r < 4; r++) {
        const int m = g4 * 4 + r;
        if (initZero) {
            hreg[r][0] = 0.0f;
            hreg[r][1] = 0.0f;
        } else {
            hreg[r][0] = h_state[(size_t)m * H_ + jA];
            hreg[r][1] = h_state[(size_t)m * H_ + jA + 16];
        }
        lds_h[0][m][jA]      = (_Float16)hreg[r][0];
        lds_h[0][m][jA + 16] = (_Float16)hreg[r][1];
    }
    __syncthreads();

    int cur = 0;
    for (int tt = 0; tt < Tc; ++tt) {
        // LICM barrier: opaque LDS offset each step.
        unsigned wb = (unsigned)(w * 1024 + l);
        asm volatile("" : "+v"(wb));

        // gi prefetch: issued now, consumed after the MFMA block.
        float gic[4][6];
#pragma unroll
        for (int r = 0; r < 4; r++) {
            const float* gp = gi + ((size_t)(g4 * 4 + r) * Tc + tt) * G3_ + jA;
#pragma unroll
            for (int gg = 0; gg < 3; gg++) {
                gic[r][gg * 2 + 0] = gp[gg * 256];
                gic[r][gg * 2 + 1] = gp[gg * 256 + 16];
            }
        }

        f32x4 acc[6] = {};
#pragma unroll
        for (int kt = 0; kt < 8; kt++) {
            // A-frag: lane supplies h[c][kt*32 + g4*8 .. +8]  (ds_read_b128)
            f16x8 a = *(const f16x8*)&lds_h[cur][c][kt * 32 + g4 * 8];
#pragma unroll
            for (int nt = 0; nt < 4; nt++)
                acc[nt] = __builtin_amdgcn_mfma_f32_16x16x32_f16(
                    a, __builtin_bit_cast(f16x8, wreg[nt * 8 + kt]), acc[nt], 0, 0, 0);
            uint4 u4 = lds_w[wb + kt * 64];            // nt=4 frag
            acc[4] = __builtin_amdgcn_mfma_f32_16x16x32_f16(
                a, __builtin_bit_cast(f16x8, u4), acc[4], 0, 0, 0);
            uint4 u5 = lds_w[wb + (8 + kt) * 64];      // nt=5 frag
            acc[5] = __builtin_amdgcn_mfma_f32_16x16x32_f16(
                a, __builtin_bit_cast(f16x8, u5), acc[5], 0, 0, 0);
        }

        // D layout: row m = g4*4 + reg, col = tile_c0 + c.
        // nt 0/1 = r-gate (jj=0/1), nt 2/3 = z, nt 4/5 = n.
#pragma unroll
        for (int r = 0; r < 4; r++) {
            const int m = g4 * 4 + r;
#pragma unroll
            for (int jj = 0; jj < 2; jj++) {
                float rg = sigmoid_f(gic[r][jj]     + acc[jj][r]     + (jj ? br1 : br0));
                float zg = sigmoid_f(gic[r][2 + jj] + acc[2 + jj][r] + (jj ? bz1 : bz0));
                float ng = tanh_f(gic[r][4 + jj] +
                                  rg * (acc[4 + jj][r] + (jj ? bn1 : bn0)));
                float hn = (1.0f - zg) * ng + zg * hreg[r][jj];
                hreg[r][jj] = hn;
                lds_h[cur ^ 1][m][jA + jj * 16] = (_Float16)hn;
                if (out_seq)
                    out_seq[((size_t)m * Tc + tt) * H_ + jA + jj * 16] = hn;
            }
        }
        if (tt == Tc - 1) {
#pragma unroll
            for (int r = 0; r < 4; r++) {
                const int m = g4 * 4 + r;
                h_state[(size_t)m * H_ + jA]      = hreg[r][0];
                h_state[(size_t)m * H_ + jA + 16] = hreg[r][1];
            }
        }
        __syncthreads();
        cur ^= 1;
    }
}

// Fused layer-pipelined scan: blocks 0..15 -> layer0 chunk c (16 rows each),
// blocks 16..31 -> layer1 chunk c-1. 148 KB LDS -> 1 block/CU naturally.
__global__ __launch_bounds__(512, 2) void k_gru_scan_fused(
    const float* __restrict__ gi0, const uint4* __restrict__ wl0,
    const float* __restrict__ bhh0, float* __restrict__ hst0,
    float* __restrict__ h1c,
    const float* __restrict__ gi1, const uint4* __restrict__ wl1,
    const float* __restrict__ bhh1, float* __restrict__ hst1,
    int Tc, int do0, int do1, int init0, int init1)
{
    __shared__ __align__(16) uint4    lds_w[8192];        // 128 KB
    __shared__ __align__(16) _Float16 lds_h[2][16][264];  // 16.5 KB

    const int blk = blockIdx.x;
    if (blk < 16) {
        if (!do0) return;
        const int b0 = blk * 16;
        gru_scan_core(gi0 + (size_t)b0 * Tc * G3_, wl0, bhh0,
                      hst0 + (size_t)b0 * H_, h1c + (size_t)b0 * Tc * H_,
                      Tc, init0, lds_w, lds_h);
    } else {
        if (!do1) return;
        const int b0 = (blk - 16) * 16;
        gru_scan_core(gi1 + (size_t)b0 * Tc * G3_, wl1, bhh1,
                      hst1 + (size_t)b0 * H_, nullptr,
                      Tc, init1, lds_w, lds_h);
    }
}

// ---------------------------------------------------------------------------
__global__ void k_fc(const float* __restrict__ h, const float* __restrict__ Wfc,
                     const float* __restrict__ bfc, float* __restrict__ out)
{
    int idx = blockIdx.x * blockDim.x + threadIdx.x;
    if (idx >= B_ * C_) return;
    int b = idx / C_, c = idx % C_;
    const float* hp = h + (size_t)b * H_;
    const float* wp = Wfc + (size_t)c * H_;
    float s = bfc[c];
#pragma unroll 4
    for (int k = 0; k < H_; k++) s = fmaf(hp[k], wp[k], s);
    out[idx] = s;
}

// ---------------------------------------------------------------------------
extern "C" void kernel_launch(void* const* d_in, const int* in_sizes, int n_in,
                              void* d_out, int out_size, void* d_ws, size_t ws_size,
                              hipStream_t stream)
{
    const float* x    = (const float*)d_in[0];
    const float* Wih0 = (const float*)d_in[1];
    const float* Whh0 = (const float*)d_in[2];
    const float* bih0 = (const float*)d_in[3];
    const float* bhh0 = (const float*)d_in[4];
    const float* Wih1 = (const float*)d_in[5];
    const float* Whh1 = (const float*)d_in[6];
    const float* bih1 = (const float*)d_in[7];
    const float* bhh1 = (const float*)d_in[8];
    const float* Wfc  = (const float*)d_in[9];
    const float* bfc  = (const float*)d_in[10];
    float* out = (float*)d_out;

    const size_t wlBytes  = (size_t)48 * 512 * sizeof(uint4);    // 393,216 B
    const size_t wp0Bytes = (size_t)48 * 4 * 64 * sizeof(uint4); // 196,608 B
    const size_t wp1Bytes = (size_t)48 * 8 * 64 * sizeof(uint4); // 393,216 B

    // ---- T-chunk: start at 64 (pipeline-bubble sweet spot), shrink to fit -
    const size_t fixedB = 2 * wlBytes + wp0Bytes + wp1Bytes
                        + 2 * (size_t)B_ * H_ * 4 + 16384;
    int Tc = 64, tcShift = 6;
    while (Tc > 1) {
        size_t need = fixedB
                    + 2 * (size_t)B_ * Tc * G3_ * 4    // gi0, gi1 chunks
                    + (size_t)B_ * Tc * H_ * 4;        // h1 chunk
        if (need <= ws_size) break;
        Tc >>= 1; tcShift--;
    }
    const int nChunks = T_ / Tc;

    char* ws = (char*)d_ws;
    size_t off = 0;
    auto alloc = [&](size_t bytes) { char* p = ws + off; off += (bytes + 255) & ~(size_t)255; return p; };
    float* gi0  = (float*)alloc((size_t)B_ * Tc * G3_ * 4);
    float* gi1  = (float*)alloc((size_t)B_ * Tc * G3_ * 4);
    float* h1c  = (float*)alloc((size_t)B_ * Tc * H_ * 4);
    uint4* wl0  = (uint4*)alloc(wlBytes);
    uint4* wl1  = (uint4*)alloc(wlBytes);
    uint4* wp0  = (uint4*)alloc(wp0Bytes);
    uint4* wp1  = (uint4*)alloc(wp1Bytes);
    float* hst0 = (float*)alloc((size_t)B_ * H_ * 4);
    float* hst1 = (float*)alloc((size_t)B_ * H_ * 4);

    k_pack_whh<<<48, 512, 0, stream>>>(Whh0, wl0);
    k_pack_whh<<<48, 512, 0, stream>>>(Whh1, wl1);
    k_pack_wih<<<48, 256, 0, stream>>>(Wih0, wp0, D_);   // KT=4 -> 192 frags
    k_pack_wih<<<96, 256, 0, stream>>>(Wih1, wp1, H_);   // KT=8 -> 384 frags

    const dim3 ggrid(G3_ / 128, (B_ * Tc) / 128);

    // software pipeline: fused launch c runs scan0(c) and scan1(c-1)
    k_gemm_f16<<<ggrid, 256, 0, stream>>>(
        x, (long)T_ * D_, tcShift, wp0, bih0, gi0, D_);
    k_gru_scan_fused<<<32, 512, 0, stream>>>(
        gi0, wl0, bhh0, hst0, h1c, gi1, wl1, bhh1, hst1,
        Tc, 1, 0, 1, 0);

    for (int c = 1; c < nChunks; ++c) {
        k_gemm_f16<<<ggrid, 256, 0, stream>>>(
            h1c, (long)Tc * H_, tcShift, wp1, bih1, gi1, H_);        // chunk c-1
        k_gemm_f16<<<ggrid, 256, 0, stream>>>(
            x + (size_t)c * Tc * D_, (long)T_ * D_, tcShift, wp0, bih0, gi0, D_);
        k_gru_scan_fused<<<32, 512, 0, stream>>>(
            gi0, wl0, bhh0, hst0, h1c, gi1, wl1, bhh1, hst1,
            Tc, 1, 1, 0, c == 1);
    }

    k_gemm_f16<<<ggrid, 256, 0, stream>>>(
        h1c, (long)Tc * H_, tcShift, wp1, bih1, gi1, H_);            // last chunk
    k_gru_scan_fused<<<32, 512, 0, stream>>>(
        gi0, wl0, bhh0, hst0, h1c, gi1, wl1, bhh1, hst1,
        Tc, 0, 1, 0, nChunks == 1);

    k_fc<<<10, 256, 0, stream>>>(hst1, Wfc, bfc, out);
}